// Round 7
// baseline (273.451 us; speedup 1.0000x reference)
//
#include <hip/hip_runtime.h>

// ---------------- problem constants ----------------
#define BATCH     32
#define T_SAMP    480000
#define NFRAMES   2998
#define KLEN      400
#define KF        256             // folded K: t and t+256 combined (x[t>=400]=0)
#define NMEL      80
#define EPS_F     1.1920928955078125e-07f
#define SCALE2    1073741824.0f   // 32768^2, re-applied before log (A unscaled)
#define SPLIT_S   2048.0f         // lo-plane scale
#define SPLIT_INV 4.8828125e-4f   // 1/2048
#define MTE       132             // per-parity mel filter row stride (floats)

typedef _Float16 f16x8 __attribute__((ext_vector_type(8)));
typedef float    f32x4 __attribute__((ext_vector_type(4)));

// ---------------- kernel 0: zero the means accumulator (runs before k_main) ----
__global__ __launch_bounds__(256) void FbankWrapper_14285061226526_kernel(float* means)
{
    int i = blockIdx.x * 256 + threadIdx.x;
    if (i < BATCH * NMEL) means[i] = 0.f;
}

// ---------------- kernel 1: fused setup -----------------------------------------
// DFT fold: B[bin][k+256] = (-1)^bin B[bin][k]  ->  even bins consume xe=y[k]+y[k+256],
// odd bins consume xo=y[k]-y[k+256], K=256.
// Even group (256 cols): c=0 -> bin0 re; c=1 -> bin256 re (mel weights exactly 0);
// c>=2 -> bin=2*(c>>1), re/im by c&1.  Odd group: bin=2*(c>>1)+1, re/im by c&1.
// B planes stored fp16 hi/lo, K-CHUNKED: elem (c,k) at ((k>>3)*256 + c)*8 + (k&7).
// blocks 0..79: per-parity mel filter rows (melfTe/melfTo) + slot ranges.
// blocks 80..143: B split/fold gather from the PROVIDED dcos/dsin tables.
__global__ __launch_bounds__(256) void k_prep(const float* __restrict__ melf,
                                              const float* __restrict__ dcos,
                                              const float* __restrict__ dsin,
                                              int* __restrict__ loE, int* __restrict__ hiE,
                                              int* __restrict__ loO, int* __restrict__ hiO,
                                              float* __restrict__ melfTe,
                                              float* __restrict__ melfTo,
                                              _Float16* __restrict__ Bhe, _Float16* __restrict__ Ble,
                                              _Float16* __restrict__ Bho, _Float16* __restrict__ Blo)
{
    const int bid = blockIdx.x;
    const int tid = threadIdx.x;

    if (bid < 80) {
        __shared__ int sE0, sE1, sO0, sO1;
        if (tid == 0) { sE0 = 999; sE1 = 0; sO0 = 999; sO1 = 0; }
        __syncthreads();
        const int m = bid;
        if (tid < 129) {                       // even slots: bin 0,2,...,254,256
            int bin = (tid == 0) ? 0 : (tid == 128) ? 256 : 2 * tid;
            float w = melf[(size_t)bin * NMEL + m];
            melfTe[(size_t)m * MTE + tid] = w;
            if (w > 0.f) { atomicMin(&sE0, tid); atomicMax(&sE1, tid + 1); }
        }
        if (tid < 128) {                       // odd slots: bin 1,3,...,255
            float w = melf[(size_t)(2 * tid + 1) * NMEL + m];
            melfTo[(size_t)m * MTE + tid] = w;
            if (w > 0.f) { atomicMin(&sO0, tid); atomicMax(&sO1, tid + 1); }
        }
        if (tid == 0) {
            melfTe[(size_t)m * MTE + 129] = 0.f;
            melfTe[(size_t)m * MTE + 130] = 0.f;
            melfTe[(size_t)m * MTE + 131] = 0.f;
            melfTo[(size_t)m * MTE + 128] = 0.f;
            melfTo[(size_t)m * MTE + 129] = 0.f;
            melfTo[(size_t)m * MTE + 130] = 0.f;
            melfTo[(size_t)m * MTE + 131] = 0.f;
        }
        __syncthreads();
        if (tid == 0) { loE[m] = sE0; hiE[m] = sE1; loO[m] = sO0; hiO[m] = sO1; }
        return;
    }

    int id = (bid - 80) * 256 + tid;           // 2 groups * 32 chunks * 256 cols
    if (id >= 16384) return;
    int g  = id >> 13;                         // 0 = even group, 1 = odd group
    int r  = id & 8191;
    int ch = r >> 8;                           // k-chunk 0..31
    int c  = r & 255;                          // col
    int k  = ch * 8;
    int bin; int sn;
    if (g == 0) { bin = (c == 0) ? 0 : (c == 1) ? 256 : 2 * (c >> 1); sn = (c >= 2) && (c & 1); }
    else        { bin = 2 * (c >> 1) + 1;                             sn = c & 1; }
    const float* src = (sn ? dsin : dcos) + (size_t)bin * 512 + k;
    f16x8 hv, lv;
    #pragma unroll
    for (int j = 0; j < 8; ++j) {
        float v = src[j];
        _Float16 h = (_Float16)v;
        hv[j] = h;
        lv[j] = (_Float16)((v - (float)h) * SPLIT_S);
    }
    size_t off = ((size_t)ch * 256 + c) * 8;
    *(f16x8*)((g ? Bho : Bhe) + off) = hv;
    *(f16x8*)((g ? Blo : Ble) + off) = lv;
}

// ---------------- helpers for k_main prep ----------------
__device__ inline void y8_compute(const float* __restrict__ sig,
                                  const float* __restrict__ window,
                                  int k0, float mean, float ys[8])
{
    float4 x0 = *(const float4*)(sig + k0);
    float4 x1 = *(const float4*)(sig + k0 + 4);
    float4 w0 = *(const float4*)(window + k0);
    float4 w1 = *(const float4*)(window + k0 + 4);
    float xm1 = (k0 > 0) ? sig[k0 - 1] : x0.x;
    float xs[8] = {x0.x, x0.y, x0.z, x0.w, x1.x, x1.y, x1.z, x1.w};
    float wv[8] = {w0.x, w0.y, w0.z, w0.w, w1.x, w1.y, w1.z, w1.w};
    #pragma unroll
    for (int j = 0; j < 8; ++j) {
        float xp = (j == 0) ? xm1 : xs[j - 1];
        ys[j] = (xs[j] - 0.97f * xp - 0.03f * mean) * wv[j];
    }
}

__device__ inline void split_store(_Float16* dh, _Float16* dl, const float ys[8])
{
    f16x8 hv, lv;
    #pragma unroll
    for (int j = 0; j < 8; ++j) {
        _Float16 h = (_Float16)ys[j];
        hv[j] = h;
        lv[j] = (_Float16)((ys[j] - (float)h) * SPLIT_S);
    }
    *(f16x8*)dh = hv;
    *(f16x8*)dl = lv;
}

// ---------------- kernel 2: folded split-fp16 MFMA DFT + spectrum + mel + mean --
// one block = 32 frames, 8 waves, 512 threads, 2 blocks/CU (72,832 B LDS).
// pass 0 = even bins (Ae planes, Bhe/Ble), pass 1 = odd bins (Ao for k<160,
// shares Ae tail since xo[k]=xe[k]=y[k] for k>=144; Bho/Blo).
// C = Ah*Bh + (Al*Bh + Ah*Bl)/2048, merged correction accumulator.
// Sp stride 132 floats = 132 dw === 4 (mod 32): conflict-free b128 mel reads,
// 2-way Sp writes (stride 136 === 8 was 2x worse -- round-6 lesson).
// Frame-mean fused: per-block LDS reduction -> global atomics (k_mean removed).
__global__ __launch_bounds__(512, 4) void k_main_pre(const float* __restrict__ wav,
                                                     const float* __restrict__ window,
                                                     const float* __restrict__ melfTe,
                                                     const float* __restrict__ melfTo,
                                                     const int* __restrict__ loE,
                                                     const int* __restrict__ hiE,
                                                     const int* __restrict__ loO,
                                                     const int* __restrict__ hiO,
                                                     const _Float16* __restrict__ Bhe,
                                                     const _Float16* __restrict__ Ble,
                                                     const _Float16* __restrict__ Bho,
                                                     const _Float16* __restrict__ Blo,
                                                     float* __restrict__ out,
                                                     float* __restrict__ means)
{
    __shared__ __align__(16) _Float16 Aeh[32][264];  // 16,896 B (132 dw stride: CF)
    __shared__ __align__(16) _Float16 Ael[32][264];  // 16,896 B
    __shared__ __align__(16) _Float16 Aoh[32][168];  // 10,752 B (k<160 only)
    __shared__ __align__(16) _Float16 Aol[32][168];  // 10,752 B
    __shared__ __align__(16) float    Sp[32][132];   // 16,896 B
    __shared__           float        mloc[2][80];   //    640 B  (total 72,832)

    const int tid  = threadIdx.x;
    const int lane = tid & 63;
    const int wid  = tid >> 6;              // wave 0..7
    const int tile = blockIdx.x;            // 0..2997

    // ---- prep: 16 threads/frame; mean via shuffle; fold + split to 4 planes ----
    {
        int fr = tid >> 4, og = tid & 15;
        int fb = tile * 32 + fr;
        int b  = fb / NFRAMES;
        int f  = fb - b * NFRAMES;
        const float* sig = wav + (size_t)b * T_SAMP + (size_t)f * 160;

        float s = 0.f;
        #pragma unroll
        for (int i = 0; i < 4; ++i) {
            int k0 = og * 8 + 128 * i;
            if (k0 < KLEN) {
                float4 x0 = *(const float4*)(sig + k0);
                float4 x1 = *(const float4*)(sig + k0 + 4);
                s += x0.x + x0.y + x0.z + x0.w + x1.x + x1.y + x1.z + x1.w;
            }
        }
        s += __shfl_xor(s, 1);
        s += __shfl_xor(s, 2);
        s += __shfl_xor(s, 4);
        s += __shfl_xor(s, 8);
        float mean = s * (1.0f / (float)KLEN);

        if (tid < 160) ((float*)mloc)[tid] = 0.f;   // zero the mean-reduce slots

        // fold tasks: chunks og and og+16 (8 samples each, k0 = 8c)
        #pragma unroll
        for (int t2 = 0; t2 < 2; ++t2) {
            int c  = og + 16 * t2;          // 0..31
            int k0 = c * 8;                 // 0..248
            float ys[8];
            y8_compute(sig, window, k0, mean, ys);
            if (c < 18) {                   // pairs with k0+256 (<400)
                float yb[8], ye[8], yo[8];
                y8_compute(sig, window, k0 + 256, mean, yb);
                #pragma unroll
                for (int j = 0; j < 8; ++j) { ye[j] = ys[j] + yb[j]; yo[j] = ys[j] - yb[j]; }
                split_store(&Aeh[fr][k0], &Ael[fr][k0], ye);
                split_store(&Aoh[fr][k0], &Aol[fr][k0], yo);
            } else {                        // x[k0+256]=0 -> xe=xo=y
                split_store(&Aeh[fr][k0], &Ael[fr][k0], ys);
                if (k0 < 160)
                    split_store(&Aoh[fr][k0], &Aol[fr][k0], ys);
            }
        }
    }
    __syncthreads();                        // A planes + mloc ready

    const int q  = lane >> 4, lr = lane & 15;
    const int mf = tid & 31;                // mel: frame
    const int mg = tid >> 5;                // mel: 0..15 (mels mg+16t, t=0..4)

    float accm[5];
    #pragma unroll
    for (int t = 0; t < 5; ++t) accm[t] = 0.f;

    #pragma unroll
    for (int p = 0; p < 2; ++p) {
        f32x4 aM[2][2], aC[2][2];
        #pragma unroll
        for (int mt = 0; mt < 2; ++mt)
            #pragma unroll
            for (int nt = 0; nt < 2; ++nt) {
                aM[mt][nt] = (f32x4){0.f, 0.f, 0.f, 0.f};
                aC[mt][nt] = (f32x4){0.f, 0.f, 0.f, 0.f};
            }

        const _Float16* Bh_ = p ? Bho : Bhe;
        const _Float16* Bl_ = p ? Blo : Ble;
        const _Float16* bph[2];
        const _Float16* blp[2];
        #pragma unroll
        for (int nt = 0; nt < 2; ++nt) {
            int c = wid * 32 + nt * 16 + lr;            // col within group, 0..255
            size_t off = (size_t)q * 2048 + (size_t)c * 8;
            bph[nt] = Bh_ + off;
            blp[nt] = Bl_ + off;
        }

        // ---- K loop: 8 steps of 32; pass1 reads Ao for k<160, Ae tail after ----
        #pragma unroll
        for (int s = 0; s < 8; ++s) {
            const int kk = s * 32;
            f16x8 ah[2], al[2], bh[2], bl[2];
            if (p == 0 || s >= 5) {
                #pragma unroll
                for (int mt = 0; mt < 2; ++mt) {
                    ah[mt] = *(const f16x8*)&Aeh[mt * 16 + lr][kk + q * 8];
                    al[mt] = *(const f16x8*)&Ael[mt * 16 + lr][kk + q * 8];
                }
            } else {
                #pragma unroll
                for (int mt = 0; mt < 2; ++mt) {
                    ah[mt] = *(const f16x8*)&Aoh[mt * 16 + lr][kk + q * 8];
                    al[mt] = *(const f16x8*)&Aol[mt * 16 + lr][kk + q * 8];
                }
            }
            #pragma unroll
            for (int nt = 0; nt < 2; ++nt) {
                bh[nt] = *(const f16x8*)(bph[nt] + (size_t)s * 8192);
                bl[nt] = *(const f16x8*)(blp[nt] + (size_t)s * 8192);
            }
            #pragma unroll
            for (int mt = 0; mt < 2; ++mt)
                #pragma unroll
                for (int nt = 0; nt < 2; ++nt)
                    aM[mt][nt] = __builtin_amdgcn_mfma_f32_16x16x32_f16(
                        ah[mt], bh[nt], aM[mt][nt], 0, 0, 0);
            #pragma unroll
            for (int mt = 0; mt < 2; ++mt)
                #pragma unroll
                for (int nt = 0; nt < 2; ++nt)
                    aC[mt][nt] = __builtin_amdgcn_mfma_f32_16x16x32_f16(
                        al[mt], bh[nt], aC[mt][nt], 0, 0, 0);
            #pragma unroll
            for (int mt = 0; mt < 2; ++mt)
                #pragma unroll
                for (int nt = 0; nt < 2; ++nt)
                    aC[mt][nt] = __builtin_amdgcn_mfma_f32_16x16x32_f16(
                        ah[mt], bl[nt], aC[mt][nt], 0, 0, 0);
        }

        // ---- spectrum epilogue: combine planes, pair re/im via shfl ----
        __syncthreads();                    // prior pass's mel Sp-reads done
        #pragma unroll
        for (int mt = 0; mt < 2; ++mt)
            #pragma unroll
            for (int nt = 0; nt < 2; ++nt)
                #pragma unroll
                for (int r = 0; r < 4; ++r) {
                    float v = aM[mt][nt][r] + aC[mt][nt][r] * SPLIT_INV;
                    float o = __shfl_xor(v, 1);
                    int row = mt * 16 + q * 4 + r;                 // frame 0..31
                    if (p == 0 && wid == 0 && nt == 0 && lr < 2) {
                        // even-group cols 0/1 = bin0/bin256 re-only (mel weight 0;
                        // slot 128 exists only as write target, never read)
                        if (lr == 0) Sp[row][0] = v * v;
                    } else if ((lane & 1) == 0) {
                        int slot = (wid * 32 + nt * 16 + lr) >> 1; // 0..127
                        Sp[row][slot] = v * v + o * o;
                    }
                }
        __syncthreads();                    // Sp visible

        // ---- mel partial-accumulate for this parity; zero-padded over-reads ----
        const float* mfT = p ? melfTo : melfTe;
        const int*   loP = p ? loO : loE;
        const int*   hiP = p ? hiO : hiE;
        #pragma unroll
        for (int t = 0; t < 5; ++t) {
            int m  = mg + 16 * t;
            int ks = loP[m], ke = hiP[m];
            const float* wrow = mfT + (size_t)m * MTE;
            for (int k4 = ks & ~3; k4 < ke; k4 += 4) {
                f32x4  sv = *(const f32x4*)&Sp[mf][k4];
                float4 wv = *(const float4*)(wrow + k4);
                accm[t] += sv[0] * wv.x + sv[1] * wv.y + sv[2] * wv.z + sv[3] * wv.w;
            }
        }
    }

    // ---- re-apply 32768^2, log, fp32 store + fused per-(batch,mel) mean sums ----
    {
        int fb = tile * 32 + mf;
        int b  = fb / NFRAMES;
        int b0 = (tile * 32) / NFRAMES;
        size_t row = (size_t)fb;
        float lg[5];
        #pragma unroll
        for (int t = 0; t < 5; ++t) {
            lg[t] = logf(fmaxf(accm[t] * SCALE2, EPS_F));
            out[row * NMEL + mg + 16 * t] = lg[t];
        }
        #pragma unroll
        for (int t = 0; t < 5; ++t)
            atomicAdd(&mloc[b - b0][mg + 16 * t], lg[t]);
        __syncthreads();
        if (tid < 160) {
            int bo = tid / 80, m = tid - bo * 80;
            int bb = b0 + bo;
            if (bb < BATCH)
                atomicAdd(&means[bb * NMEL + m], mloc[bo][m]);
        }
    }
}

// ---------------- kernel 3: subtract mean in-place (fp32) ----------
__global__ __launch_bounds__(256) void k_norm(const float* __restrict__ means,
                                              float* __restrict__ out)
{
    const int PER = NFRAMES * NMEL;           // 239,840
    int b = blockIdx.y;
    int e = blockIdx.x * 256 + threadIdx.x;
    if (e < PER) {
        int m = e % NMEL;
        size_t idx = (size_t)b * PER + e;
        out[idx] = out[idx] - means[b * NMEL + m] * (1.0f / (float)NFRAMES);
    }
}

// ---------------- launch ----------------
extern "C" void kernel_launch(void* const* d_in, const int* in_sizes, int n_in,
                              void* d_out, int out_size, void* d_ws, size_t ws_size,
                              hipStream_t stream)
{
    const float* wav    = (const float*)d_in[0];
    const float* window = (const float*)d_in[1];
    const float* melf   = (const float*)d_in[2];
    const float* dcos   = (const float*)d_in[3];
    const float* dsin   = (const float*)d_in[4];
    float* out = (float*)d_out;

    // ws layout (620,544 B; harness proved >= 946,176 usable in rounds 2-5):
    //   means  fp32 32*80        @ 0        (10,240)
    //   loE/hiE/loO/hiO int 80*4 @ 10,240   (1,280)
    //   melfTe fp32 80*132       @ 11,520   (42,240)
    //   melfTo fp32 80*132       @ 53,760   (42,240)  -> 96,000 (pad to 96,256)
    //   Bhe f16 32*256*8         @ 96,256   (131,072)
    //   Ble f16                  @ 227,328  (131,072)
    //   Bho f16                  @ 358,400  (131,072)
    //   Blo f16                  @ 489,472  (131,072) -> 620,544
    char* ws = (char*)d_ws;
    float*     means  = (float*)ws;
    int*       loE    = (int*)(ws + 10240);
    int*       hiE    = (int*)(ws + 10560);
    int*       loO    = (int*)(ws + 10880);
    int*       hiO    = (int*)(ws + 11200);
    float*     melfTe = (float*)(ws + 11520);
    float*     melfTo = (float*)(ws + 53760);
    _Float16*  Bhe    = (_Float16*)(ws + 96256);
    _Float16*  Ble    = (_Float16*)(ws + 227328);
    _Float16*  Bho    = (_Float16*)(ws + 358400);
    _Float16*  Blo    = (_Float16*)(ws + 489472);

    FbankWrapper_14285061226526_kernel<<<10, 256, 0, stream>>>(means);
    k_prep<<<144, 256, 0, stream>>>(melf, dcos, dsin, loE, hiE, loO, hiO,
                                    melfTe, melfTo, Bhe, Ble, Bho, Blo);
    k_main_pre<<<2998, 512, 0, stream>>>(wav, window, melfTe, melfTo,
                                         loE, hiE, loO, hiO,
                                         Bhe, Ble, Bho, Blo, out, means);
    k_norm<<<dim3((NFRAMES * NMEL + 255) / 256, BATCH), 256, 0, stream>>>(means, out);
}

// Round 8
// 271.940 us; speedup vs baseline: 1.0056x; 1.0056x over previous
//
#include <hip/hip_runtime.h>

// ---------------- problem constants ----------------
#define BATCH     32
#define T_SAMP    480000
#define NFRAMES   2998
#define KLEN      400
#define KF        256             // folded K: t and t+256 combined (x[t>=400]=0)
#define NMEL      80
#define EPS_F     1.1920928955078125e-07f
#define SCALE2    1073741824.0f   // 32768^2, re-applied before log (A unscaled)
#define SPLIT_S   2048.0f         // lo-plane scale
#define SPLIT_INV 4.8828125e-4f   // 1/2048
#define MTE       132             // per-parity mel filter row stride (floats)

typedef _Float16 f16x8 __attribute__((ext_vector_type(8)));
typedef float    f32x4 __attribute__((ext_vector_type(4)));

// ---------------- kernel 0: zero the means accumulator (runs before k_main) ----
__global__ __launch_bounds__(256) void FbankWrapper_14285061226526_kernel(float* means)
{
    int i = blockIdx.x * 256 + threadIdx.x;
    if (i < BATCH * NMEL) means[i] = 0.f;
}

// ---------------- kernel 1: fused setup -----------------------------------------
// DFT fold: B[bin][k+256] = (-1)^bin B[bin][k]  ->  even bins consume xe=y[k]+y[k+256],
// odd bins consume xo=y[k]-y[k+256], K=256.
// Even group (256 cols): c=0 -> bin0 re; c=1 -> bin256 re (mel weights exactly 0);
// c>=2 -> bin=2*(c>>1), re/im by c&1.  Odd group: bin=2*(c>>1)+1, re/im by c&1.
// B planes stored fp16 hi/lo, K-CHUNKED: elem (c,k) at ((k>>3)*256 + c)*8 + (k&7).
// blocks 0..79: per-parity mel filter rows (melfTe/melfTo) + slot ranges.
// blocks 80..143: B split/fold gather from the PROVIDED dcos/dsin tables.
__global__ __launch_bounds__(256) void k_prep(const float* __restrict__ melf,
                                              const float* __restrict__ dcos,
                                              const float* __restrict__ dsin,
                                              int* __restrict__ loE, int* __restrict__ hiE,
                                              int* __restrict__ loO, int* __restrict__ hiO,
                                              float* __restrict__ melfTe,
                                              float* __restrict__ melfTo,
                                              _Float16* __restrict__ Bhe, _Float16* __restrict__ Ble,
                                              _Float16* __restrict__ Bho, _Float16* __restrict__ Blo)
{
    const int bid = blockIdx.x;
    const int tid = threadIdx.x;

    if (bid < 80) {
        __shared__ int sE0, sE1, sO0, sO1;
        if (tid == 0) { sE0 = 999; sE1 = 0; sO0 = 999; sO1 = 0; }
        __syncthreads();
        const int m = bid;
        if (tid < 129) {                       // even slots: bin 0,2,...,254,256
            int bin = (tid == 0) ? 0 : (tid == 128) ? 256 : 2 * tid;
            float w = melf[(size_t)bin * NMEL + m];
            melfTe[(size_t)m * MTE + tid] = w;
            if (w > 0.f) { atomicMin(&sE0, tid); atomicMax(&sE1, tid + 1); }
        }
        if (tid < 128) {                       // odd slots: bin 1,3,...,255
            float w = melf[(size_t)(2 * tid + 1) * NMEL + m];
            melfTo[(size_t)m * MTE + tid] = w;
            if (w > 0.f) { atomicMin(&sO0, tid); atomicMax(&sO1, tid + 1); }
        }
        if (tid == 0) {
            melfTe[(size_t)m * MTE + 129] = 0.f;
            melfTe[(size_t)m * MTE + 130] = 0.f;
            melfTe[(size_t)m * MTE + 131] = 0.f;
            melfTo[(size_t)m * MTE + 128] = 0.f;
            melfTo[(size_t)m * MTE + 129] = 0.f;
            melfTo[(size_t)m * MTE + 130] = 0.f;
            melfTo[(size_t)m * MTE + 131] = 0.f;
        }
        __syncthreads();
        if (tid == 0) { loE[m] = sE0; hiE[m] = sE1; loO[m] = sO0; hiO[m] = sO1; }
        return;
    }

    int id = (bid - 80) * 256 + tid;           // 2 groups * 32 chunks * 256 cols
    if (id >= 16384) return;
    int g  = id >> 13;                         // 0 = even group, 1 = odd group
    int r  = id & 8191;
    int ch = r >> 8;                           // k-chunk 0..31
    int c  = r & 255;                          // col
    int k  = ch * 8;
    int bin; int sn;
    if (g == 0) { bin = (c == 0) ? 0 : (c == 1) ? 256 : 2 * (c >> 1); sn = (c >= 2) && (c & 1); }
    else        { bin = 2 * (c >> 1) + 1;                             sn = c & 1; }
    const float* src = (sn ? dsin : dcos) + (size_t)bin * 512 + k;
    f16x8 hv, lv;
    #pragma unroll
    for (int j = 0; j < 8; ++j) {
        float v = src[j];
        _Float16 h = (_Float16)v;
        hv[j] = h;
        lv[j] = (_Float16)((v - (float)h) * SPLIT_S);
    }
    size_t off = ((size_t)ch * 256 + c) * 8;
    *(f16x8*)((g ? Bho : Bhe) + off) = hv;
    *(f16x8*)((g ? Blo : Ble) + off) = lv;
}

// ---------------- helpers for k_main prep ----------------
__device__ inline void y8_compute(const float* __restrict__ sig,
                                  const float* __restrict__ window,
                                  int k0, float mean, float ys[8])
{
    float4 x0 = *(const float4*)(sig + k0);
    float4 x1 = *(const float4*)(sig + k0 + 4);
    float4 w0 = *(const float4*)(window + k0);
    float4 w1 = *(const float4*)(window + k0 + 4);
    float xm1 = (k0 > 0) ? sig[k0 - 1] : x0.x;
    float xs[8] = {x0.x, x0.y, x0.z, x0.w, x1.x, x1.y, x1.z, x1.w};
    float wv[8] = {w0.x, w0.y, w0.z, w0.w, w1.x, w1.y, w1.z, w1.w};
    #pragma unroll
    for (int j = 0; j < 8; ++j) {
        float xp = (j == 0) ? xm1 : xs[j - 1];
        ys[j] = (xs[j] - 0.97f * xp - 0.03f * mean) * wv[j];
    }
}

__device__ inline void split_store(_Float16* dh, _Float16* dl, const float ys[8])
{
    f16x8 hv, lv;
    #pragma unroll
    for (int j = 0; j < 8; ++j) {
        _Float16 h = (_Float16)ys[j];
        hv[j] = h;
        lv[j] = (_Float16)((ys[j] - (float)h) * SPLIT_S);
    }
    *(f16x8*)dh = hv;
    *(f16x8*)dl = lv;
}

// ---------------- kernel 2: folded split-fp16 MFMA DFT + spectrum + mel + mean --
// one block = 32 frames, 8 waves, 512 threads, 2 blocks/CU (72,704 B LDS).
// pass 0 = even bins (Ae planes, Bhe/Ble), pass 1 = odd bins (Ao for k<160,
// shares Ae tail since xo[k]=xe[k]=y[k] for k>=144; Bho/Blo).
// C = Ah*Bh + (Al*Bh + Ah*Bl)/2048, merged correction accumulator.
// Sp stride 132 dw === 4 (mod 32): conflict-free b128 mel reads, 2-way writes.
// Frame-mean fused via HALF-WAVE SHUFFLE reduction (mg = tid>>5 is constant per
// 32-lane half-wave, mf = tid&31 spans the 32 frames) -> one global atomicAdd per
// (half-wave, t) from the mf==0 lane.  Round-7 lesson: LDS atomicAdd with 32-way
// same-address contention cost ~44 us; shuffles are free on the VALU.
__global__ __launch_bounds__(512, 4) void k_main_pre(const float* __restrict__ wav,
                                                     const float* __restrict__ window,
                                                     const float* __restrict__ melfTe,
                                                     const float* __restrict__ melfTo,
                                                     const int* __restrict__ loE,
                                                     const int* __restrict__ hiE,
                                                     const int* __restrict__ loO,
                                                     const int* __restrict__ hiO,
                                                     const _Float16* __restrict__ Bhe,
                                                     const _Float16* __restrict__ Ble,
                                                     const _Float16* __restrict__ Bho,
                                                     const _Float16* __restrict__ Blo,
                                                     float* __restrict__ out,
                                                     float* __restrict__ means)
{
    __shared__ __align__(16) _Float16 Aeh[32][264];  // 16,896 B (132 dw stride: CF)
    __shared__ __align__(16) _Float16 Ael[32][264];  // 16,896 B
    __shared__ __align__(16) _Float16 Aoh[32][168];  // 10,752 B (k<160 only)
    __shared__ __align__(16) _Float16 Aol[32][168];  // 10,752 B
    __shared__ __align__(16) float    Sp[32][132];   // 16,896 B  (72,192 total)

    const int tid  = threadIdx.x;
    const int lane = tid & 63;
    const int wid  = tid >> 6;              // wave 0..7
    const int tile = blockIdx.x;            // 0..2997

    // ---- prep: 16 threads/frame; mean via shuffle; fold + split to 4 planes ----
    {
        int fr = tid >> 4, og = tid & 15;
        int fb = tile * 32 + fr;
        int b  = fb / NFRAMES;
        int f  = fb - b * NFRAMES;
        const float* sig = wav + (size_t)b * T_SAMP + (size_t)f * 160;

        float s = 0.f;
        #pragma unroll
        for (int i = 0; i < 4; ++i) {
            int k0 = og * 8 + 128 * i;
            if (k0 < KLEN) {
                float4 x0 = *(const float4*)(sig + k0);
                float4 x1 = *(const float4*)(sig + k0 + 4);
                s += x0.x + x0.y + x0.z + x0.w + x1.x + x1.y + x1.z + x1.w;
            }
        }
        s += __shfl_xor(s, 1);
        s += __shfl_xor(s, 2);
        s += __shfl_xor(s, 4);
        s += __shfl_xor(s, 8);
        float mean = s * (1.0f / (float)KLEN);

        // fold tasks: chunks og and og+16 (8 samples each, k0 = 8c)
        #pragma unroll
        for (int t2 = 0; t2 < 2; ++t2) {
            int c  = og + 16 * t2;          // 0..31
            int k0 = c * 8;                 // 0..248
            float ys[8];
            y8_compute(sig, window, k0, mean, ys);
            if (c < 18) {                   // pairs with k0+256 (<400)
                float yb[8], ye[8], yo[8];
                y8_compute(sig, window, k0 + 256, mean, yb);
                #pragma unroll
                for (int j = 0; j < 8; ++j) { ye[j] = ys[j] + yb[j]; yo[j] = ys[j] - yb[j]; }
                split_store(&Aeh[fr][k0], &Ael[fr][k0], ye);
                split_store(&Aoh[fr][k0], &Aol[fr][k0], yo);
            } else {                        // x[k0+256]=0 -> xe=xo=y
                split_store(&Aeh[fr][k0], &Ael[fr][k0], ys);
                if (k0 < 160)
                    split_store(&Aoh[fr][k0], &Aol[fr][k0], ys);
            }
        }
    }
    __syncthreads();                        // A planes ready

    const int q  = lane >> 4, lr = lane & 15;
    const int mf = tid & 31;                // mel: frame
    const int mg = tid >> 5;                // mel: 0..15 (mels mg+16t, t=0..4)

    float accm[5];
    #pragma unroll
    for (int t = 0; t < 5; ++t) accm[t] = 0.f;

    #pragma unroll
    for (int p = 0; p < 2; ++p) {
        f32x4 aM[2][2], aC[2][2];
        #pragma unroll
        for (int mt = 0; mt < 2; ++mt)
            #pragma unroll
            for (int nt = 0; nt < 2; ++nt) {
                aM[mt][nt] = (f32x4){0.f, 0.f, 0.f, 0.f};
                aC[mt][nt] = (f32x4){0.f, 0.f, 0.f, 0.f};
            }

        const _Float16* Bh_ = p ? Bho : Bhe;
        const _Float16* Bl_ = p ? Blo : Ble;
        const _Float16* bph[2];
        const _Float16* blp[2];
        #pragma unroll
        for (int nt = 0; nt < 2; ++nt) {
            int c = wid * 32 + nt * 16 + lr;            // col within group, 0..255
            size_t off = (size_t)q * 2048 + (size_t)c * 8;
            bph[nt] = Bh_ + off;
            blp[nt] = Bl_ + off;
        }

        // ---- K loop: 8 steps of 32; pass1 reads Ao for k<160, Ae tail after ----
        #pragma unroll
        for (int s = 0; s < 8; ++s) {
            const int kk = s * 32;
            f16x8 ah[2], al[2], bh[2], bl[2];
            if (p == 0 || s >= 5) {
                #pragma unroll
                for (int mt = 0; mt < 2; ++mt) {
                    ah[mt] = *(const f16x8*)&Aeh[mt * 16 + lr][kk + q * 8];
                    al[mt] = *(const f16x8*)&Ael[mt * 16 + lr][kk + q * 8];
                }
            } else {
                #pragma unroll
                for (int mt = 0; mt < 2; ++mt) {
                    ah[mt] = *(const f16x8*)&Aoh[mt * 16 + lr][kk + q * 8];
                    al[mt] = *(const f16x8*)&Aol[mt * 16 + lr][kk + q * 8];
                }
            }
            #pragma unroll
            for (int nt = 0; nt < 2; ++nt) {
                bh[nt] = *(const f16x8*)(bph[nt] + (size_t)s * 8192);
                bl[nt] = *(const f16x8*)(blp[nt] + (size_t)s * 8192);
            }
            #pragma unroll
            for (int mt = 0; mt < 2; ++mt)
                #pragma unroll
                for (int nt = 0; nt < 2; ++nt)
                    aM[mt][nt] = __builtin_amdgcn_mfma_f32_16x16x32_f16(
                        ah[mt], bh[nt], aM[mt][nt], 0, 0, 0);
            #pragma unroll
            for (int mt = 0; mt < 2; ++mt)
                #pragma unroll
                for (int nt = 0; nt < 2; ++nt)
                    aC[mt][nt] = __builtin_amdgcn_mfma_f32_16x16x32_f16(
                        al[mt], bh[nt], aC[mt][nt], 0, 0, 0);
            #pragma unroll
            for (int mt = 0; mt < 2; ++mt)
                #pragma unroll
                for (int nt = 0; nt < 2; ++nt)
                    aC[mt][nt] = __builtin_amdgcn_mfma_f32_16x16x32_f16(
                        ah[mt], bl[nt], aC[mt][nt], 0, 0, 0);
        }

        // ---- spectrum epilogue: combine planes, pair re/im via shfl ----
        __syncthreads();                    // prior pass's mel Sp-reads done
        #pragma unroll
        for (int mt = 0; mt < 2; ++mt)
            #pragma unroll
            for (int nt = 0; nt < 2; ++nt)
                #pragma unroll
                for (int r = 0; r < 4; ++r) {
                    float v = aM[mt][nt][r] + aC[mt][nt][r] * SPLIT_INV;
                    float o = __shfl_xor(v, 1);
                    int row = mt * 16 + q * 4 + r;                 // frame 0..31
                    if (p == 0 && wid == 0 && nt == 0 && lr < 2) {
                        // even-group cols 0/1 = bin0/bin256, re-only, mel weight 0.
                        // slot 0 written (finite filler); bin256 has no slot.
                        if (lr == 0) Sp[row][0] = v * v;
                    } else if ((lane & 1) == 0) {
                        int slot = (wid * 32 + nt * 16 + lr) >> 1; // 0..127
                        Sp[row][slot] = v * v + o * o;
                    }
                }
        __syncthreads();                    // Sp visible

        // ---- mel partial-accumulate for this parity; zero-padded over-reads ----
        const float* mfT = p ? melfTo : melfTe;
        const int*   loP = p ? loO : loE;
        const int*   hiP = p ? hiO : hiE;
        #pragma unroll
        for (int t = 0; t < 5; ++t) {
            int m  = mg + 16 * t;
            int ks = loP[m], ke = hiP[m];
            const float* wrow = mfT + (size_t)m * MTE;
            for (int k4 = ks & ~3; k4 < ke; k4 += 4) {
                f32x4  sv = *(const f32x4*)&Sp[mf][k4];
                float4 wv = *(const float4*)(wrow + k4);
                accm[t] += sv[0] * wv.x + sv[1] * wv.y + sv[2] * wv.z + sv[3] * wv.w;
            }
        }
    }

    // ---- log + store + fused frame-mean via half-wave shuffle reduction ----
    {
        int fb = tile * 32 + mf;
        int b  = fb / NFRAMES;
        int b0 = (tile * 32) / NFRAMES;            // batch of tile's frame 0
        int bL = (tile * 32 + 31) / NFRAMES;       // batch of tile's frame 31
        size_t row = (size_t)fb;
        float lg[5];
        #pragma unroll
        for (int t = 0; t < 5; ++t) {
            lg[t] = logf(fmaxf(accm[t] * SCALE2, EPS_F));
            out[row * NMEL + mg + 16 * t] = lg[t];
        }
        if (bL == b0) {                            // common case: no batch straddle
            #pragma unroll
            for (int t = 0; t < 5; ++t) {
                float v = lg[t];
                #pragma unroll
                for (int d = 1; d < 32; d <<= 1) v += __shfl_xor(v, d);
                if (mf == 0)
                    atomicAdd(&means[b0 * NMEL + mg + 16 * t], v);
            }
        } else {                                   // straddle (31/2998 tiles)
            #pragma unroll
            for (int t = 0; t < 5; ++t) {
                float v0 = (b == b0) ? lg[t] : 0.f;
                float v1 = lg[t] - v0;
                #pragma unroll
                for (int d = 1; d < 32; d <<= 1) {
                    v0 += __shfl_xor(v0, d);
                    v1 += __shfl_xor(v1, d);
                }
                if (mf == 0) {
                    atomicAdd(&means[b0 * NMEL + mg + 16 * t], v0);
                    atomicAdd(&means[bL * NMEL + mg + 16 * t], v1);
                }
            }
        }
    }
}

// ---------------- kernel 3: subtract mean in-place (fp32) ----------
__global__ __launch_bounds__(256) void k_norm(const float* __restrict__ means,
                                              float* __restrict__ out)
{
    const int PER = NFRAMES * NMEL;           // 239,840
    int b = blockIdx.y;
    int e = blockIdx.x * 256 + threadIdx.x;
    if (e < PER) {
        int m = e % NMEL;
        size_t idx = (size_t)b * PER + e;
        out[idx] = out[idx] - means[b * NMEL + m] * (1.0f / (float)NFRAMES);
    }
}

// ---------------- launch ----------------
extern "C" void kernel_launch(void* const* d_in, const int* in_sizes, int n_in,
                              void* d_out, int out_size, void* d_ws, size_t ws_size,
                              hipStream_t stream)
{
    const float* wav    = (const float*)d_in[0];
    const float* window = (const float*)d_in[1];
    const float* melf   = (const float*)d_in[2];
    const float* dcos   = (const float*)d_in[3];
    const float* dsin   = (const float*)d_in[4];
    float* out = (float*)d_out;

    // ws layout (620,544 B; harness proved >= 946,176 usable in rounds 2-5):
    //   means  fp32 32*80        @ 0        (10,240)
    //   loE/hiE/loO/hiO int 80*4 @ 10,240   (1,280)
    //   melfTe fp32 80*132       @ 11,520   (42,240)
    //   melfTo fp32 80*132       @ 53,760   (42,240)  -> 96,000 (pad to 96,256)
    //   Bhe f16 32*256*8         @ 96,256   (131,072)
    //   Ble f16                  @ 227,328  (131,072)
    //   Bho f16                  @ 358,400  (131,072)
    //   Blo f16                  @ 489,472  (131,072) -> 620,544
    char* ws = (char*)d_ws;
    float*     means  = (float*)ws;
    int*       loE    = (int*)(ws + 10240);
    int*       hiE    = (int*)(ws + 10560);
    int*       loO    = (int*)(ws + 10880);
    int*       hiO    = (int*)(ws + 11200);
    float*     melfTe = (float*)(ws + 11520);
    float*     melfTo = (float*)(ws + 53760);
    _Float16*  Bhe    = (_Float16*)(ws + 96256);
    _Float16*  Ble    = (_Float16*)(ws + 227328);
    _Float16*  Bho    = (_Float16*)(ws + 358400);
    _Float16*  Blo    = (_Float16*)(ws + 489472);

    FbankWrapper_14285061226526_kernel<<<10, 256, 0, stream>>>(means);
    k_prep<<<144, 256, 0, stream>>>(melf, dcos, dsin, loE, hiE, loO, hiO,
                                    melfTe, melfTo, Bhe, Ble, Bho, Blo);
    k_main_pre<<<2998, 512, 0, stream>>>(wav, window, melfTe, melfTo,
                                         loE, hiE, loO, hiO,
                                         Bhe, Ble, Bho, Blo, out, means);
    k_norm<<<dim3((NFRAMES * NMEL + 255) / 256, BATCH), 256, 0, stream>>>(means, out);
}

// Round 9
// 250.994 us; speedup vs baseline: 1.0895x; 1.0835x over previous
//
#include <hip/hip_runtime.h>

// ---------------- problem constants ----------------
#define BATCH     32
#define T_SAMP    480000
#define NFRAMES   2998
#define KLEN      400
#define KF        256             // folded K: t and t+256 combined (x[t>=400]=0)
#define NMEL      80
#define EPS_F     1.1920928955078125e-07f
#define SCALE2    1073741824.0f   // 32768^2, re-applied before log (A unscaled)
#define SPLIT_S   2048.0f         // lo-plane scale
#define SPLIT_INV 4.8828125e-4f   // 1/2048
#define MTE       132             // per-parity mel filter row stride (floats)
#define NPART     16              // mean-accumulator spread (atomic hot-spot fix)

typedef _Float16 f16x8 __attribute__((ext_vector_type(8)));
typedef float    f32x4 __attribute__((ext_vector_type(4)));

// ---------------- kernel 0: zero the spread mean partials (runs first) ---------
__global__ __launch_bounds__(256) void FbankWrapper_14285061226526_kernel(float* mpart)
{
    int i = blockIdx.x * 256 + threadIdx.x;
    if (i < NPART * BATCH * NMEL) mpart[i] = 0.f;
}

// ---------------- kernel 1: fused setup -----------------------------------------
// DFT fold: B[bin][k+256] = (-1)^bin B[bin][k]  ->  even bins consume xe=y[k]+y[k+256],
// odd bins consume xo=y[k]-y[k+256], K=256.
// Even group (256 cols): c=0 -> bin0 re; c=1 -> bin256 re (mel weights exactly 0);
// c>=2 -> bin=2*(c>>1), re/im by c&1.  Odd group: bin=2*(c>>1)+1, re/im by c&1.
// B planes stored fp16 hi/lo, K-CHUNKED: elem (c,k) at ((k>>3)*256 + c)*8 + (k&7).
// blocks 0..79: per-parity mel filter rows (melfTe/melfTo) + slot ranges.
// blocks 80..143: B split/fold gather from the PROVIDED dcos/dsin tables.
__global__ __launch_bounds__(256) void k_prep(const float* __restrict__ melf,
                                              const float* __restrict__ dcos,
                                              const float* __restrict__ dsin,
                                              int* __restrict__ loE, int* __restrict__ hiE,
                                              int* __restrict__ loO, int* __restrict__ hiO,
                                              float* __restrict__ melfTe,
                                              float* __restrict__ melfTo,
                                              _Float16* __restrict__ Bhe, _Float16* __restrict__ Ble,
                                              _Float16* __restrict__ Bho, _Float16* __restrict__ Blo)
{
    const int bid = blockIdx.x;
    const int tid = threadIdx.x;

    if (bid < 80) {
        __shared__ int sE0, sE1, sO0, sO1;
        if (tid == 0) { sE0 = 999; sE1 = 0; sO0 = 999; sO1 = 0; }
        __syncthreads();
        const int m = bid;
        if (tid < 129) {                       // even slots: bin 0,2,...,254,256
            int bin = (tid == 0) ? 0 : (tid == 128) ? 256 : 2 * tid;
            float w = melf[(size_t)bin * NMEL + m];
            melfTe[(size_t)m * MTE + tid] = w;
            if (w > 0.f) { atomicMin(&sE0, tid); atomicMax(&sE1, tid + 1); }
        }
        if (tid < 128) {                       // odd slots: bin 1,3,...,255
            float w = melf[(size_t)(2 * tid + 1) * NMEL + m];
            melfTo[(size_t)m * MTE + tid] = w;
            if (w > 0.f) { atomicMin(&sO0, tid); atomicMax(&sO1, tid + 1); }
        }
        if (tid == 0) {
            melfTe[(size_t)m * MTE + 129] = 0.f;
            melfTe[(size_t)m * MTE + 130] = 0.f;
            melfTe[(size_t)m * MTE + 131] = 0.f;
            melfTo[(size_t)m * MTE + 128] = 0.f;
            melfTo[(size_t)m * MTE + 129] = 0.f;
            melfTo[(size_t)m * MTE + 130] = 0.f;
            melfTo[(size_t)m * MTE + 131] = 0.f;
        }
        __syncthreads();
        if (tid == 0) { loE[m] = sE0; hiE[m] = sE1; loO[m] = sO0; hiO[m] = sO1; }
        return;
    }

    int id = (bid - 80) * 256 + tid;           // 2 groups * 32 chunks * 256 cols
    if (id >= 16384) return;
    int g  = id >> 13;                         // 0 = even group, 1 = odd group
    int r  = id & 8191;
    int ch = r >> 8;                           // k-chunk 0..31
    int c  = r & 255;                          // col
    int k  = ch * 8;
    int bin; int sn;
    if (g == 0) { bin = (c == 0) ? 0 : (c == 1) ? 256 : 2 * (c >> 1); sn = (c >= 2) && (c & 1); }
    else        { bin = 2 * (c >> 1) + 1;                             sn = c & 1; }
    const float* src = (sn ? dsin : dcos) + (size_t)bin * 512 + k;
    f16x8 hv, lv;
    #pragma unroll
    for (int j = 0; j < 8; ++j) {
        float v = src[j];
        _Float16 h = (_Float16)v;
        hv[j] = h;
        lv[j] = (_Float16)((v - (float)h) * SPLIT_S);
    }
    size_t off = ((size_t)ch * 256 + c) * 8;
    *(f16x8*)((g ? Bho : Bhe) + off) = hv;
    *(f16x8*)((g ? Blo : Ble) + off) = lv;
}

// ---------------- helpers for k_main prep ----------------
__device__ inline void y8_compute(const float* __restrict__ sig,
                                  const float* __restrict__ window,
                                  int k0, float mean, float ys[8])
{
    float4 x0 = *(const float4*)(sig + k0);
    float4 x1 = *(const float4*)(sig + k0 + 4);
    float4 w0 = *(const float4*)(window + k0);
    float4 w1 = *(const float4*)(window + k0 + 4);
    float xm1 = (k0 > 0) ? sig[k0 - 1] : x0.x;
    float xs[8] = {x0.x, x0.y, x0.z, x0.w, x1.x, x1.y, x1.z, x1.w};
    float wv[8] = {w0.x, w0.y, w0.z, w0.w, w1.x, w1.y, w1.z, w1.w};
    #pragma unroll
    for (int j = 0; j < 8; ++j) {
        float xp = (j == 0) ? xm1 : xs[j - 1];
        ys[j] = (xs[j] - 0.97f * xp - 0.03f * mean) * wv[j];
    }
}

__device__ inline void split_store(_Float16* dh, _Float16* dl, const float ys[8])
{
    f16x8 hv, lv;
    #pragma unroll
    for (int j = 0; j < 8; ++j) {
        _Float16 h = (_Float16)ys[j];
        hv[j] = h;
        lv[j] = (_Float16)((ys[j] - (float)h) * SPLIT_S);
    }
    *(f16x8*)dh = hv;
    *(f16x8*)dl = lv;
}

// ---------------- kernel 2: folded split-fp16 MFMA DFT + spectrum + mel + mean --
// one block = 32 frames, 8 waves, 512 threads, 2 blocks/CU (72,192 B LDS).
// pass 0 = even bins (Ae planes, Bhe/Ble), pass 1 = odd bins (Ao for k<160,
// shares Ae tail since xo[k]=xe[k]=y[k] for k>=144; Bho/Blo).
// C = Ah*Bh + (Al*Bh + Ah*Bl)/2048, merged correction accumulator.
// Sp stride 132 dw === 4 (mod 32).
// Frame-mean fused via half-wave shuffle (mg const per half-wave, mf spans the 32
// frames) -> one atomicAdd per (half-wave, t) into mpart[tile & 15] -- the 16-way
// spread removes the round-7/8 device-atomic hot-spot (240k atomics on 80 words
// dilated k_main by ~36 us; WRITE_SIZE evidence 29.9->33.8 MB).
__global__ __launch_bounds__(512, 4) void k_main_pre(const float* __restrict__ wav,
                                                     const float* __restrict__ window,
                                                     const float* __restrict__ melfTe,
                                                     const float* __restrict__ melfTo,
                                                     const int* __restrict__ loE,
                                                     const int* __restrict__ hiE,
                                                     const int* __restrict__ loO,
                                                     const int* __restrict__ hiO,
                                                     const _Float16* __restrict__ Bhe,
                                                     const _Float16* __restrict__ Ble,
                                                     const _Float16* __restrict__ Bho,
                                                     const _Float16* __restrict__ Blo,
                                                     float* __restrict__ out,
                                                     float* __restrict__ mpart)
{
    __shared__ __align__(16) _Float16 Aeh[32][264];  // 16,896 B (132 dw stride)
    __shared__ __align__(16) _Float16 Ael[32][264];  // 16,896 B
    __shared__ __align__(16) _Float16 Aoh[32][168];  // 10,752 B (k<160 only)
    __shared__ __align__(16) _Float16 Aol[32][168];  // 10,752 B
    __shared__ __align__(16) float    Sp[32][132];   // 16,896 B  (72,192 total)

    const int tid  = threadIdx.x;
    const int lane = tid & 63;
    const int wid  = tid >> 6;              // wave 0..7
    const int tile = blockIdx.x;            // 0..2997

    // ---- prep: 16 threads/frame; mean via shuffle; fold + split to 4 planes ----
    {
        int fr = tid >> 4, og = tid & 15;
        int fb = tile * 32 + fr;
        int b  = fb / NFRAMES;
        int f  = fb - b * NFRAMES;
        const float* sig = wav + (size_t)b * T_SAMP + (size_t)f * 160;

        float s = 0.f;
        #pragma unroll
        for (int i = 0; i < 4; ++i) {
            int k0 = og * 8 + 128 * i;
            if (k0 < KLEN) {
                float4 x0 = *(const float4*)(sig + k0);
                float4 x1 = *(const float4*)(sig + k0 + 4);
                s += x0.x + x0.y + x0.z + x0.w + x1.x + x1.y + x1.z + x1.w;
            }
        }
        s += __shfl_xor(s, 1);
        s += __shfl_xor(s, 2);
        s += __shfl_xor(s, 4);
        s += __shfl_xor(s, 8);
        float mean = s * (1.0f / (float)KLEN);

        // fold tasks: chunks og and og+16 (8 samples each, k0 = 8c)
        #pragma unroll
        for (int t2 = 0; t2 < 2; ++t2) {
            int c  = og + 16 * t2;          // 0..31
            int k0 = c * 8;                 // 0..248
            float ys[8];
            y8_compute(sig, window, k0, mean, ys);
            if (c < 18) {                   // pairs with k0+256 (<400)
                float yb[8], ye[8], yo[8];
                y8_compute(sig, window, k0 + 256, mean, yb);
                #pragma unroll
                for (int j = 0; j < 8; ++j) { ye[j] = ys[j] + yb[j]; yo[j] = ys[j] - yb[j]; }
                split_store(&Aeh[fr][k0], &Ael[fr][k0], ye);
                split_store(&Aoh[fr][k0], &Aol[fr][k0], yo);
            } else {                        // x[k0+256]=0 -> xe=xo=y
                split_store(&Aeh[fr][k0], &Ael[fr][k0], ys);
                if (k0 < 160)
                    split_store(&Aoh[fr][k0], &Aol[fr][k0], ys);
            }
        }
    }
    __syncthreads();                        // A planes ready

    const int q  = lane >> 4, lr = lane & 15;
    const int mf = tid & 31;                // mel: frame
    const int mg = tid >> 5;                // mel: 0..15 (mels mg+16t, t=0..4)

    float accm[5];
    #pragma unroll
    for (int t = 0; t < 5; ++t) accm[t] = 0.f;

    #pragma unroll
    for (int p = 0; p < 2; ++p) {
        f32x4 aM[2][2], aC[2][2];
        #pragma unroll
        for (int mt = 0; mt < 2; ++mt)
            #pragma unroll
            for (int nt = 0; nt < 2; ++nt) {
                aM[mt][nt] = (f32x4){0.f, 0.f, 0.f, 0.f};
                aC[mt][nt] = (f32x4){0.f, 0.f, 0.f, 0.f};
            }

        const _Float16* Bh_ = p ? Bho : Bhe;
        const _Float16* Bl_ = p ? Blo : Ble;
        const _Float16* bph[2];
        const _Float16* blp[2];
        #pragma unroll
        for (int nt = 0; nt < 2; ++nt) {
            int c = wid * 32 + nt * 16 + lr;            // col within group, 0..255
            size_t off = (size_t)q * 2048 + (size_t)c * 8;
            bph[nt] = Bh_ + off;
            blp[nt] = Bl_ + off;
        }

        // ---- K loop: 8 steps of 32; pass1 reads Ao for k<160, Ae tail after ----
        #pragma unroll
        for (int s = 0; s < 8; ++s) {
            const int kk = s * 32;
            f16x8 ah[2], al[2], bh[2], bl[2];
            if (p == 0 || s >= 5) {
                #pragma unroll
                for (int mt = 0; mt < 2; ++mt) {
                    ah[mt] = *(const f16x8*)&Aeh[mt * 16 + lr][kk + q * 8];
                    al[mt] = *(const f16x8*)&Ael[mt * 16 + lr][kk + q * 8];
                }
            } else {
                #pragma unroll
                for (int mt = 0; mt < 2; ++mt) {
                    ah[mt] = *(const f16x8*)&Aoh[mt * 16 + lr][kk + q * 8];
                    al[mt] = *(const f16x8*)&Aol[mt * 16 + lr][kk + q * 8];
                }
            }
            #pragma unroll
            for (int nt = 0; nt < 2; ++nt) {
                bh[nt] = *(const f16x8*)(bph[nt] + (size_t)s * 8192);
                bl[nt] = *(const f16x8*)(blp[nt] + (size_t)s * 8192);
            }
            #pragma unroll
            for (int mt = 0; mt < 2; ++mt)
                #pragma unroll
                for (int nt = 0; nt < 2; ++nt)
                    aM[mt][nt] = __builtin_amdgcn_mfma_f32_16x16x32_f16(
                        ah[mt], bh[nt], aM[mt][nt], 0, 0, 0);
            #pragma unroll
            for (int mt = 0; mt < 2; ++mt)
                #pragma unroll
                for (int nt = 0; nt < 2; ++nt)
                    aC[mt][nt] = __builtin_amdgcn_mfma_f32_16x16x32_f16(
                        al[mt], bh[nt], aC[mt][nt], 0, 0, 0);
            #pragma unroll
            for (int mt = 0; mt < 2; ++mt)
                #pragma unroll
                for (int nt = 0; nt < 2; ++nt)
                    aC[mt][nt] = __builtin_amdgcn_mfma_f32_16x16x32_f16(
                        ah[mt], bl[nt], aC[mt][nt], 0, 0, 0);
        }

        // ---- spectrum epilogue: combine planes, pair re/im via shfl ----
        __syncthreads();                    // prior pass's mel Sp-reads done
        #pragma unroll
        for (int mt = 0; mt < 2; ++mt)
            #pragma unroll
            for (int nt = 0; nt < 2; ++nt)
                #pragma unroll
                for (int r = 0; r < 4; ++r) {
                    float v = aM[mt][nt][r] + aC[mt][nt][r] * SPLIT_INV;
                    float o = __shfl_xor(v, 1);
                    int row = mt * 16 + q * 4 + r;                 // frame 0..31
                    if (p == 0 && wid == 0 && nt == 0 && lr < 2) {
                        // even-group cols 0/1 = bin0/bin256, re-only, mel weight 0.
                        if (lr == 0) Sp[row][0] = v * v;
                    } else if ((lane & 1) == 0) {
                        int slot = (wid * 32 + nt * 16 + lr) >> 1; // 0..127
                        Sp[row][slot] = v * v + o * o;
                    }
                }
        __syncthreads();                    // Sp visible

        // ---- mel partial-accumulate for this parity; zero-padded over-reads ----
        const float* mfT = p ? melfTo : melfTe;
        const int*   loP = p ? loO : loE;
        const int*   hiP = p ? hiO : hiE;
        #pragma unroll
        for (int t = 0; t < 5; ++t) {
            int m  = mg + 16 * t;
            int ks = loP[m], ke = hiP[m];
            const float* wrow = mfT + (size_t)m * MTE;
            for (int k4 = ks & ~3; k4 < ke; k4 += 4) {
                f32x4  sv = *(const f32x4*)&Sp[mf][k4];
                float4 wv = *(const float4*)(wrow + k4);
                accm[t] += sv[0] * wv.x + sv[1] * wv.y + sv[2] * wv.z + sv[3] * wv.w;
            }
        }
    }

    // ---- log + store + fused frame-mean via half-wave shuffle reduction ----
    {
        int fb = tile * 32 + mf;
        int b  = fb / NFRAMES;
        int b0 = (tile * 32) / NFRAMES;            // batch of tile's frame 0
        int bL = (tile * 32 + 31) / NFRAMES;       // batch of tile's frame 31
        size_t row = (size_t)fb;
        float* mp = mpart + (size_t)(tile & (NPART - 1)) * (BATCH * NMEL);
        float lg[5];
        #pragma unroll
        for (int t = 0; t < 5; ++t) {
            lg[t] = logf(fmaxf(accm[t] * SCALE2, EPS_F));
            out[row * NMEL + mg + 16 * t] = lg[t];
        }
        if (bL == b0) {                            // common case: no batch straddle
            #pragma unroll
            for (int t = 0; t < 5; ++t) {
                float v = lg[t];
                #pragma unroll
                for (int d = 1; d < 32; d <<= 1) v += __shfl_xor(v, d);
                if (mf == 0)
                    atomicAdd(&mp[b0 * NMEL + mg + 16 * t], v);
            }
        } else {                                   // straddle (31/2998 tiles)
            #pragma unroll
            for (int t = 0; t < 5; ++t) {
                float v0 = (b == b0) ? lg[t] : 0.f;
                float v1 = lg[t] - v0;
                #pragma unroll
                for (int d = 1; d < 32; d <<= 1) {
                    v0 += __shfl_xor(v0, d);
                    v1 += __shfl_xor(v1, d);
                }
                if (mf == 0) {
                    atomicAdd(&mp[b0 * NMEL + mg + 16 * t], v0);
                    atomicAdd(&mp[bL * NMEL + mg + 16 * t], v1);
                }
            }
        }
    }
}

// ---------------- kernel 3: fold the 16 mean partials -> means ----------
__global__ __launch_bounds__(256) void k_red(const float* __restrict__ mpart,
                                             float* __restrict__ means)
{
    int i = blockIdx.x * 256 + threadIdx.x;
    if (i < BATCH * NMEL) {
        float s = 0.f;
        #pragma unroll
        for (int p = 0; p < NPART; ++p) s += mpart[(size_t)p * BATCH * NMEL + i];
        means[i] = s;
    }
}

// ---------------- kernel 4: subtract mean in-place (fp32) ----------
__global__ __launch_bounds__(256) void k_norm(const float* __restrict__ means,
                                              float* __restrict__ out)
{
    const int PER = NFRAMES * NMEL;           // 239,840
    int b = blockIdx.y;
    int e = blockIdx.x * 256 + threadIdx.x;
    if (e < PER) {
        int m = e % NMEL;
        size_t idx = (size_t)b * PER + e;
        out[idx] = out[idx] - means[b * NMEL + m] * (1.0f / (float)NFRAMES);
    }
}

// ---------------- launch ----------------
extern "C" void kernel_launch(void* const* d_in, const int* in_sizes, int n_in,
                              void* d_out, int out_size, void* d_ws, size_t ws_size,
                              hipStream_t stream)
{
    const float* wav    = (const float*)d_in[0];
    const float* window = (const float*)d_in[1];
    const float* melf   = (const float*)d_in[2];
    const float* dcos   = (const float*)d_in[3];
    const float* dsin   = (const float*)d_in[4];
    float* out = (float*)d_out;

    // ws layout (784,384 B; harness proved >= 946,176 usable in rounds 2-5):
    //   means  fp32 32*80        @ 0        (10,240)
    //   loE/hiE/loO/hiO int 80*4 @ 10,240   (1,280)
    //   melfTe fp32 80*132       @ 11,520   (42,240)
    //   melfTo fp32 80*132       @ 53,760   (42,240)  -> 96,000 (pad to 96,256)
    //   Bhe f16 32*256*8         @ 96,256   (131,072)
    //   Ble f16                  @ 227,328  (131,072)
    //   Bho f16                  @ 358,400  (131,072)
    //   Blo f16                  @ 489,472  (131,072) -> 620,544
    //   mpart fp32 16*32*80      @ 620,544  (163,840) -> 784,384
    char* ws = (char*)d_ws;
    float*     means  = (float*)ws;
    int*       loE    = (int*)(ws + 10240);
    int*       hiE    = (int*)(ws + 10560);
    int*       loO    = (int*)(ws + 10880);
    int*       hiO    = (int*)(ws + 11200);
    float*     melfTe = (float*)(ws + 11520);
    float*     melfTo = (float*)(ws + 53760);
    _Float16*  Bhe    = (_Float16*)(ws + 96256);
    _Float16*  Ble    = (_Float16*)(ws + 227328);
    _Float16*  Bho    = (_Float16*)(ws + 358400);
    _Float16*  Blo    = (_Float16*)(ws + 489472);
    float*     mpart  = (float*)(ws + 620544);

    FbankWrapper_14285061226526_kernel<<<160, 256, 0, stream>>>(mpart);
    k_prep<<<144, 256, 0, stream>>>(melf, dcos, dsin, loE, hiE, loO, hiO,
                                    melfTe, melfTo, Bhe, Ble, Bho, Blo);
    k_main_pre<<<2998, 512, 0, stream>>>(wav, window, melfTe, melfTo,
                                         loE, hiE, loO, hiO,
                                         Bhe, Ble, Bho, Blo, out, mpart);
    k_red<<<10, 256, 0, stream>>>(mpart, means);
    k_norm<<<dim3((NFRAMES * NMEL + 255) / 256, BATCH), 256, 0, stream>>>(means, out);
}